// Round 4
// baseline (284.836 us; speedup 1.0000x reference)
//
#include <hip/hip_runtime.h>

// Problem constants
#define MDIM 8192
#define IDIM 1024
#define ODIM 1024
#define D1   9            // DEGREE+1
#define KDIM (IDIM * D1)  // 9216, k = d*1024 + i ordering

typedef _Float16 half8   __attribute__((ext_vector_type(8)));
typedef float    float4v __attribute__((ext_vector_type(4)));

#define BSCALE 256.0f     // pre-scale B into f16-normal range (exact pow2)
#define INV_BSCALE (1.0f / 256.0f)
#define USCALE 5.123105625617661f    // sqrt(17) + 1
#define H0C 0.7511255444649425f     // pi^-1/4
#define SQRT2 1.4142135623730951f   // h1 = sqrt2 * u * h0

__device__ __forceinline__ half8 splat8(float f) {
    _Float16 h = (_Float16)f;
    return half8{h, h, h, h, h, h, h, h};
}

// ---------------------------------------------------------------------------
// hermite9 (fp32) — naive fallback only.
// ---------------------------------------------------------------------------
__device__ __forceinline__ void hermite9(float xv, float h[D1]) {
    float ax = fabsf(xv);
    float t  = __expf(-2.0f * ax);
    float th = (1.0f - t) / (1.0f + t);
    th = copysignf(th, xv);
    float u = th * USCALE;
    float g = __expf(-0.5f * u * u);
    h[0] = H0C * g;
    h[1] = SQRT2 * H0C * u * g;
    const float c1[D1] = {0.f, 0.f, 1.0f, 0.8164965809277260f, 0.7071067811865476f,
                          0.6324555320336759f, 0.5773502691896258f, 0.5345224838248488f, 0.5f};
    const float c2[D1] = {0.f, 0.f, 0.7071067811865476f, 0.8164965809277260f, 0.8660254037844386f,
                          0.8944271909999159f, 0.9128709291752769f, 0.9258200997725514f, 0.9354143466934853f};
#pragma unroll
    for (int d = 2; d < D1; ++d) h[d] = c1[d] * u * h[d - 1] - c2[d] * h[d - 2];
}

// ---------------------------------------------------------------------------
// prep_all: one launch, two bodies (wave-uniform split on blockIdx).
//  blocks [0,1024):      prep_b — LDS-transpose coeffs fp32 [I][O][9] ->
//                        Bt f16 [O][K] * 256, coalesced both phases.
//  blocks [1024, 5120):  prep_u — x -> u = USCALE*tanh(x), h0 = pi^-1/4*gauss,
//                        both f16, half8 stores. rcp instead of divide.
// ---------------------------------------------------------------------------
__global__ __launch_bounds__(256) void prep_all(const float* __restrict__ C,
                                                _Float16* __restrict__ Bt,
                                                const float* __restrict__ x,
                                                _Float16* __restrict__ U,
                                                _Float16* __restrict__ H0) {
    if (blockIdx.x < 1024) {
        __shared__ float lds[288 * 33];
        const int t  = threadIdx.x;
        const int ti = blockIdx.x & 31;
        const int to = blockIdx.x >> 5;
        const float* base = C + (size_t)ti * 32 * 9216 + (size_t)to * 32 * 9;
#pragma unroll
        for (int j = 0; j < 36; ++j) {
            int f   = t + 256 * j;
            int row = f / 288;
            int col = f - row * 288;
            lds[col * 33 + row] = base[(size_t)row * 9216 + col];
        }
        __syncthreads();
        _Float16* bb = Bt + (size_t)to * 32 * KDIM + ti * 32;
#pragma unroll
        for (int j = 0; j < 36; ++j) {
            int e   = t + 256 * j;
            int i   = e & 31;
            int odp = e >> 5;
            int ol  = odp / 9;
            int d   = odp - ol * 9;
            bb[(size_t)ol * KDIM + d * IDIM + i] = (_Float16)(lds[odp * 33 + i] * BSCALE);
        }
    } else {
        size_t t = (size_t)(blockIdx.x - 1024) * 256 + threadIdx.x;
        const float4* xp = (const float4*)(x + t * 8);
        float4 a0 = xp[0], a1 = xp[1];
        float xv[8] = {a0.x, a0.y, a0.z, a0.w, a1.x, a1.y, a1.z, a1.w};
        half8 uu, hh;
#pragma unroll
        for (int e = 0; e < 8; ++e) {
            float v  = xv[e];
            float t2 = __expf(-2.0f * fabsf(v));
            float th = (1.0f - t2) * __builtin_amdgcn_rcpf(1.0f + t2);
            float u  = copysignf(th, v) * USCALE;
            float g  = __expf(-0.5f * u * u);
            uu[e] = (_Float16)u;
            hh[e] = (_Float16)(H0C * g);
        }
        *(half8*)(U  + t * 8) = uu;
        *(half8*)(H0 + t * 8) = hh;
    }
}

// ---------------------------------------------------------------------------
// gemm_fused3: A-operands generated IN REGISTERS (no As LDS at all).
// Each lane owns 8 (frag i<4, ko<2) k-windows of u / h_{d-1} / h_d in half8
// regs, matching the MFMA A-layout A[m=lane&15][k=8q+j] exactly; advancing d
// is 12 pk-f16 ops per window. Bs (16 KB) double-buffered via global_load_lds;
// ONE barrier per step at the TOP — the Bs[nxt] DMA issued after it has a
// full step of MFMA (~1244 cyc/CU) to land, so the drain at the next barrier
// is ~free. XOR-swizzled Bs (0 conflicts). 128x128 tile, 4 waves 2x2.
// ---------------------------------------------------------------------------
__global__ __launch_bounds__(256, 2) void gemm_fused3(
    const _Float16* __restrict__ U,    // [8192][1024] f16
    const _Float16* __restrict__ H0,   // [8192][1024] f16
    const _Float16* __restrict__ Bt,   // [ODIM][KDIM], pre-scaled by 256
    float* __restrict__ out)           // [8192][ODIM]
{
    const int tid = threadIdx.x;
    const int w = tid >> 6;
    const int l = tid & 63;
    const int bn = blockIdx.x;    // n-tile 0..7  (= XCD id for L2-hot B panel)
    const int bm = blockIdx.y;    // m-tile 0..63

    __shared__ _Float16 Bs[2][128 * 64];

    // Bs staging: lane l, rep rr loads 16B; stored kgrp = (l&7)^(l>>3)
    const int lrow8 = l >> 3;
    const int kgrp  = (l & 7) ^ lrow8;
    const _Float16* Bg = Bt + ((size_t)(bn * 128 + w * 8 + lrow8) * KDIM + kgrp * 8);

    // fragment indices
    const int q   = l >> 4;
    const int m16 = l & 15;
    const int s3  = m16 & 7;
    const int wm  = w >> 1, wn = w & 1;

    // A-state: (frag i<4, ko<2) k-windows; lane holds i-cols [8q+32ko .. +7]
    half8 u2[4][2], hA[4][2], hB[4][2];
    const size_t arow = ((size_t)(bm * 128 + wm * 64 + m16)) << 10;
    const _Float16* Ubase = U  + arow + 8 * q;
    const _Float16* Hbase = H0 + arow + 8 * q;

    auto loadUH = [&](int kb) {   // loads u2 and hA(=h0) only; hB set at d==0
#pragma unroll
        for (int i = 0; i < 4; ++i)
#pragma unroll
            for (int ko = 0; ko < 2; ++ko) {
                size_t off = ((size_t)(i * 16) << 10) + kb + 32 * ko;
                u2[i][ko] = *(const half8*)(Ubase + off);
                hA[i][ko] = *(const half8*)(Hbase + off);
            }
    };

    float4v acc[4][4] = {};
    const half8 sq2v = splat8(SQRT2);

    constexpr float c1a[D1] = {0.f, 0.f, 1.0f, 0.8164965809277260f, 0.7071067811865476f,
                               0.6324555320336759f, 0.5773502691896258f, 0.5345224838248488f, 0.5f};
    constexpr float c2a[D1] = {0.f, 0.f, 0.7071067811865476f, 0.8164965809277260f, 0.8660254037844386f,
                               0.8944271909999159f, 0.9128709291752769f, 0.9258200997725514f, 0.9354143466934853f};

    // ---- prologue: DMA Bs[0] for (ib=0,d=0); start u/h0 loads
#pragma unroll
    for (int rr = 0; rr < 4; ++rr)
        __builtin_amdgcn_global_load_lds(
            (const __attribute__((address_space(1))) void*)(Bg + (size_t)(rr * 32) * KDIM),
            (__attribute__((address_space(3))) void*)((char*)&Bs[0][0] + (rr * 4 + w) * 1024),
            16, 0, 0);
    loadUH(0);

    for (int ib = 0; ib < 16; ++ib) {
        const int kbase = ib * 64;
#pragma unroll
        for (int d = 0; d < D1; ++d) {
            const int cur = (ib + d) & 1;   // parity of step ib*9+d (9 odd)
            const int nxt = cur ^ 1;

            // (1) barrier: publishes Bs[cur] (DMA'd last step, fully landed)
            //     and guarantees last step's Bs[nxt] reads are done.
            __syncthreads();

            // (2) issue next step's Bs DMA — has the whole step to land
            const bool has_next = (d < 8) || (ib < 15);
            if (has_next) {
                const int nkoff = (d == 8) ? (kbase + 64) : ((d + 1) * IDIM + kbase);
#pragma unroll
                for (int rr = 0; rr < 4; ++rr)
                    __builtin_amdgcn_global_load_lds(
                        (const __attribute__((address_space(1))) void*)(Bg + (size_t)(rr * 32) * KDIM + nkoff),
                        (__attribute__((address_space(3))) void*)((char*)&Bs[nxt][0] + (rr * 4 + w) * 1024),
                        16, 0, 0);
            }

            // (3) A-operands for this d, in registers (pk-f16 pipe)
            half8 af[4][2];
            if (d == 0) {
#pragma unroll
                for (int i = 0; i < 4; ++i)
#pragma unroll
                    for (int ko = 0; ko < 2; ++ko) {
                        hB[i][ko] = sq2v * u2[i][ko] * hA[i][ko];   // h1
                        af[i][ko] = hA[i][ko];                      // h0
                    }
            } else if (d == 1) {
#pragma unroll
                for (int i = 0; i < 4; ++i)
#pragma unroll
                    for (int ko = 0; ko < 2; ++ko) af[i][ko] = hB[i][ko];
            } else if (d < 8) {
                const half8 c1v = splat8(c1a[d]);
                const half8 c2v = splat8(c2a[d]);
#pragma unroll
                for (int i = 0; i < 4; ++i)
#pragma unroll
                    for (int ko = 0; ko < 2; ++ko) {
                        half8 t  = u2[i][ko] * hB[i][ko];
                        half8 ht = c1v * t - c2v * hA[i][ko];
                        hA[i][ko] = hB[i][ko];
                        hB[i][ko] = ht;
                        af[i][ko] = ht;
                    }
            } else {  // d == 8: last degree — no state rotation needed
                const half8 c1v = splat8(c1a[8]);
                const half8 c2v = splat8(c2a[8]);
#pragma unroll
                for (int i = 0; i < 4; ++i)
#pragma unroll
                    for (int ko = 0; ko < 2; ++ko) {
                        half8 t = u2[i][ko] * hB[i][ko];
                        af[i][ko] = c1v * t - c2v * hA[i][ko];
                    }
                if (ib < 15) loadUH(kbase + 64);   // next i-block's u/h0
            }

            // (4) MFMA: B frags from swizzled LDS, A frags from registers
#pragma unroll
            for (int ko = 0; ko < 2; ++ko) {
                const int slot = (q + 4 * ko) ^ s3;
                half8 bf[4];
#pragma unroll
                for (int j = 0; j < 4; ++j)
                    bf[j] = *(const half8*)&Bs[cur][(wn * 64 + j * 16 + m16) * 64 + slot * 8];
#pragma unroll
                for (int i = 0; i < 4; ++i)
#pragma unroll
                    for (int j = 0; j < 4; ++j)
                        acc[i][j] = __builtin_amdgcn_mfma_f32_16x16x32_f16(af[i][ko], bf[j], acc[i][j], 0, 0, 0);
            }
        }
    }

    // epilogue: D row = quad*4 + reg, col = lane&15 (m89-verified layout)
#pragma unroll
    for (int i = 0; i < 4; ++i) {
        int row = bm * 128 + wm * 64 + i * 16 + q * 4;
#pragma unroll
        for (int j = 0; j < 4; ++j) {
            int col = bn * 128 + wn * 64 + j * 16 + m16;
            float* op = out + (size_t)row * ODIM + col;
#pragma unroll
            for (int r2 = 0; r2 < 4; ++r2)
                op[(size_t)r2 * ODIM] = acc[i][j][r2] * INV_BSCALE;
        }
    }
}

// ---------------------------------------------------------------------------
// naive fallback (only if workspace can't hold Bt + U + H0, 52.4 MB)
// ---------------------------------------------------------------------------
__global__ void naive_kernel(const float* __restrict__ x, const float* __restrict__ C,
                             float* __restrict__ out) {
    __shared__ float hb[IDIM * D1];
    int b = blockIdx.x;
    int tid = threadIdx.x;
    for (int i = tid; i < IDIM; i += 256) {
        float h[D1];
        hermite9(x[(size_t)b * IDIM + i], h);
#pragma unroll
        for (int d = 0; d < D1; ++d) hb[i * D1 + d] = h[d];
    }
    __syncthreads();
    for (int o = tid; o < ODIM; o += 256) {
        float acc = 0.f;
        for (int i = 0; i < IDIM; ++i) {
            const float* cp = C + ((size_t)i * ODIM + o) * D1;
            const float* hp = hb + i * D1;
#pragma unroll
            for (int d = 0; d < D1; ++d) acc += hp[d] * cp[d];
        }
        out[(size_t)b * ODIM + o] = acc;
    }
}

// ---------------------------------------------------------------------------
extern "C" void kernel_launch(void* const* d_in, const int* in_sizes, int n_in,
                              void* d_out, int out_size, void* d_ws, size_t ws_size,
                              hipStream_t stream) {
    const float* x      = (const float*)d_in[0];   // [8192][1024]
    const float* coeffs = (const float*)d_in[1];   // [1024][1024][9]
    float* out = (float*)d_out;                    // [8192][1024]

    const size_t bt_bytes = (size_t)ODIM * KDIM * sizeof(_Float16);   // 18.9 MB
    const size_t u_bytes  = (size_t)MDIM * IDIM * sizeof(_Float16);   // 16.8 MB

    if (ws_size >= bt_bytes + 2 * u_bytes) {
        _Float16* Bt = (_Float16*)d_ws;
        _Float16* Uv = (_Float16*)((char*)d_ws + bt_bytes);
        _Float16* H0 = (_Float16*)((char*)d_ws + bt_bytes + u_bytes);
        hipLaunchKernelGGL(prep_all, dim3(1024 + (MDIM * IDIM) / 2048), dim3(256), 0, stream,
                           coeffs, Bt, x, Uv, H0);
        hipLaunchKernelGGL(gemm_fused3, dim3(8, 64), dim3(256), 0, stream, Uv, H0, Bt, out);
    } else {
        hipLaunchKernelGGL(naive_kernel, dim3(MDIM), dim3(256), 0, stream, x, coeffs, out);
    }
}